// Round 2
// baseline (3566.334 us; speedup 1.0000x reference)
//
#include <hip/hip_runtime.h>

#define NUM_USERS 100000
#define NUM_ITEMS 50000
#define N_NODES   150000   // NUM_USERS + NUM_ITEMS
#define DIM       64
#define NNZ_C     10000000
#define BATCH_C   4096
#define NCHUNKS   147      // ceil(150000 / 1024)

// ---------------- CSR build ----------------

__global__ __launch_bounds__(256) void count_kernel(const int* __restrict__ dst,
                                                    int* __restrict__ cnt) {
    int i = blockIdx.x * blockDim.x + threadIdx.x;
    int stride = gridDim.x * blockDim.x;
    for (; i < NNZ_C; i += stride) atomicAdd(&cnt[dst[i]], 1);
}

// Per-chunk (1024 elems) exclusive scan; chunk totals out.
__global__ __launch_bounds__(256) void scanA_kernel(const int* __restrict__ cnt,
                                                    int* __restrict__ row_ptr,
                                                    int* __restrict__ chunk_sums) {
    __shared__ int sh[256];
    int b = blockIdx.x, t = threadIdx.x;
    int base = b * 1024 + t * 4;
    int v0 = (base + 0 < N_NODES) ? cnt[base + 0] : 0;
    int v1 = (base + 1 < N_NODES) ? cnt[base + 1] : 0;
    int v2 = (base + 2 < N_NODES) ? cnt[base + 2] : 0;
    int v3 = (base + 3 < N_NODES) ? cnt[base + 3] : 0;
    int s = v0 + v1 + v2 + v3;
    sh[t] = s;
    __syncthreads();
    for (int off = 1; off < 256; off <<= 1) {
        int x = (t >= off) ? sh[t - off] : 0;
        __syncthreads();
        sh[t] += x;
        __syncthreads();
    }
    int excl = sh[t] - s;
    if (t == 255) chunk_sums[b] = sh[255];
    int run = excl;
    if (base + 0 < N_NODES) { row_ptr[base + 0] = run; run += v0; }
    if (base + 1 < N_NODES) { row_ptr[base + 1] = run; run += v1; }
    if (base + 2 < N_NODES) { row_ptr[base + 2] = run; run += v2; }
    if (base + 3 < N_NODES) { row_ptr[base + 3] = run; run += v3; }
}

__global__ void scanB_kernel(int* __restrict__ chunk_sums) {
    if (threadIdx.x == 0 && blockIdx.x == 0) {
        int run = 0;
        for (int i = 0; i < NCHUNKS; ++i) {
            int c = chunk_sums[i];
            chunk_sums[i] = run;
            run += c;
        }
    }
}

__global__ __launch_bounds__(256) void scanC_kernel(int* __restrict__ row_ptr,
                                                    int* __restrict__ cursor,
                                                    const int* __restrict__ chunk_offs) {
    int i = blockIdx.x * blockDim.x + threadIdx.x;
    if (i < N_NODES) {
        int v = row_ptr[i] + chunk_offs[i >> 10];
        row_ptr[i] = v;
        cursor[i] = v;
    } else if (i == N_NODES) {
        row_ptr[i] = NNZ_C;
    }
}

__global__ __launch_bounds__(256) void scatter_kernel(const int* __restrict__ src,
                                                      const int* __restrict__ dst,
                                                      const float* __restrict__ val,
                                                      int2* __restrict__ packed,
                                                      int* __restrict__ cursor) {
    int i = blockIdx.x * blockDim.x + threadIdx.x;
    int stride = gridDim.x * blockDim.x;
    for (; i < NNZ_C; i += stride) {
        int d = dst[i];
        int p = atomicAdd(&cursor[d], 1);
        packed[p] = make_int2(src[i], __float_as_int(val[i]));
    }
}

// ---------------- SpMM (gather, 1 wave per dst node) ----------------

template <bool FIRST>
__global__ __launch_bounds__(256) void spmm_kernel(const int2* __restrict__ packed,
                                                   const int* __restrict__ row_ptr,
                                                   const float* __restrict__ xin,
                                                   const float* __restrict__ uemb,
                                                   const float* __restrict__ iemb,
                                                   float* __restrict__ xout) {
    int gtid = blockIdx.x * blockDim.x + threadIdx.x;
    int node = gtid >> 6;
    int lane = threadIdx.x & 63;
    if (node >= N_NODES) return;
    int beg = row_ptr[node];
    int end = row_ptr[node + 1];
    float acc = 0.f;
    for (int e = beg; e < end; ++e) {
        int2 p = packed[e];
        const float* row;
        if (FIRST) {
            row = (p.x < NUM_USERS) ? (uemb + (size_t)p.x * DIM)
                                    : (iemb + (size_t)(p.x - NUM_USERS) * DIM);
        } else {
            row = xin + (size_t)p.x * DIM;
        }
        acc = fmaf(__int_as_float(p.y), row[lane], acc);
    }
    xout[(size_t)node * DIM + lane] = acc;
}

// ---------------- selected-row accumulation + dot ----------------

__global__ __launch_bounds__(256) void init_sel_kernel(const int* __restrict__ users,
                                                       const int* __restrict__ items,
                                                       const float* __restrict__ uemb,
                                                       const float* __restrict__ iemb,
                                                       float* __restrict__ acc_sel) {
    int gtid = blockIdx.x * blockDim.x + threadIdx.x;
    int idx = gtid >> 6;
    int lane = threadIdx.x & 63;
    if (idx >= 2 * BATCH_C) return;
    const float* row;
    if (idx < BATCH_C) {
        row = uemb + (size_t)users[idx] * DIM;
    } else {
        row = iemb + (size_t)items[idx - BATCH_C] * DIM;
    }
    acc_sel[(size_t)idx * DIM + lane] = row[lane];
}

__global__ __launch_bounds__(256) void add_sel_kernel(const int* __restrict__ users,
                                                      const int* __restrict__ items,
                                                      const float* __restrict__ h,
                                                      float* __restrict__ acc_sel) {
    int gtid = blockIdx.x * blockDim.x + threadIdx.x;
    int idx = gtid >> 6;
    int lane = threadIdx.x & 63;
    if (idx >= 2 * BATCH_C) return;
    int node = (idx < BATCH_C) ? users[idx] : (NUM_USERS + items[idx - BATCH_C]);
    acc_sel[(size_t)idx * DIM + lane] += h[(size_t)node * DIM + lane];
}

__global__ __launch_bounds__(256) void dot_kernel(const float* __restrict__ acc_sel,
                                                  float* __restrict__ out) {
    int gtid = blockIdx.x * blockDim.x + threadIdx.x;
    int b = gtid >> 6;
    int lane = threadIdx.x & 63;
    if (b >= BATCH_C) return;
    float u = acc_sel[(size_t)b * DIM + lane];
    float v = acc_sel[(size_t)(BATCH_C + b) * DIM + lane];
    float p = u * v;
    for (int off = 32; off > 0; off >>= 1) p += __shfl_xor(p, off);
    if (lane == 0) out[b] = p * 0.0625f;  // /4 for each of the two light_out rows
}

// ---------------- launch ----------------

extern "C" void kernel_launch(void* const* d_in, const int* in_sizes, int n_in,
                              void* d_out, int out_size, void* d_ws, size_t ws_size,
                              hipStream_t stream) {
    const int*   users = (const int*)d_in[0];
    const int*   items = (const int*)d_in[1];
    const float* uemb  = (const float*)d_in[2];
    const float* iemb  = (const float*)d_in[3];
    const int*   esrc  = (const int*)d_in[4];
    const int*   edst  = (const int*)d_in[5];
    const float* eval  = (const float*)d_in[6];
    float*       out   = (float*)d_out;

    char* ws = (char*)d_ws;
    // layout (bytes):
    int2*  packed   = (int2*)(ws + 0);             // 10M * 8B = 80,000,000
    float* hA       = (float*)(ws + 80000000);     // 38,400,000
    float* hB       = (float*)(ws + 118400000);    // 38,400,000
    float* acc_sel  = (float*)(ws + 156800000);    // 8192*64*4 = 2,097,152
    int*   row_ptr  = (int*)(ws + 158897152);      // 600,004 (pad to 600,016)
    int*   cursor   = (int*)(ws + 159497168);      // 600,000
    int*   chunk_s  = (int*)(ws + 160097168);      // 1,024
    // total ~160.1 MB

    // 1) CSR build (edge structure shared by all 3 layers)
    hipMemsetAsync(cursor, 0, N_NODES * sizeof(int), stream);
    count_kernel<<<2048, 256, 0, stream>>>(edst, cursor);
    scanA_kernel<<<NCHUNKS, 256, 0, stream>>>(cursor, row_ptr, chunk_s);
    scanB_kernel<<<1, 64, 0, stream>>>(chunk_s);
    scanC_kernel<<<(N_NODES + 256) / 256, 256, 0, stream>>>(row_ptr, cursor, chunk_s);
    scatter_kernel<<<2048, 256, 0, stream>>>(esrc, edst, eval, packed, cursor);

    // 2) acc at selected rows, layer-0 term
    init_sel_kernel<<<(2 * BATCH_C) / 4, 256, 0, stream>>>(users, items, uemb, iemb, acc_sel);

    // 3) three SpMM layers (gather form), accumulate selected rows after each
    const int spmm_blocks = N_NODES / 4;  // 1 wave per node, 4 waves per block
    spmm_kernel<true><<<spmm_blocks, 256, 0, stream>>>(packed, row_ptr, nullptr, uemb, iemb, hA);
    add_sel_kernel<<<(2 * BATCH_C) / 4, 256, 0, stream>>>(users, items, hA, acc_sel);
    spmm_kernel<false><<<spmm_blocks, 256, 0, stream>>>(packed, row_ptr, hA, nullptr, nullptr, hB);
    add_sel_kernel<<<(2 * BATCH_C) / 4, 256, 0, stream>>>(users, items, hB, acc_sel);
    spmm_kernel<false><<<spmm_blocks, 256, 0, stream>>>(packed, row_ptr, hB, nullptr, nullptr, hA);
    add_sel_kernel<<<(2 * BATCH_C) / 4, 256, 0, stream>>>(users, items, hA, acc_sel);

    // 4) final dot products
    dot_kernel<<<BATCH_C / 4, 256, 0, stream>>>(acc_sel, out);
}

// Round 3
// 1982.177 us; speedup vs baseline: 1.7992x; 1.7992x over previous
//
#include <hip/hip_runtime.h>

#define NUM_USERS 100000
#define NUM_ITEMS 50000
#define N_NODES   150000   // NUM_USERS + NUM_ITEMS
#define DIM       64
#define NNZ_C     10000000
#define BATCH_C   4096
#define NCHUNKS   147      // ceil(150000 / 1024)

// ---------------- CSR build ----------------

__global__ __launch_bounds__(256) void count_kernel(const int* __restrict__ dst,
                                                    int* __restrict__ cnt) {
    int i = blockIdx.x * blockDim.x + threadIdx.x;
    int stride = gridDim.x * blockDim.x;
    for (; i < NNZ_C; i += stride) atomicAdd(&cnt[dst[i]], 1);
}

// Per-chunk (1024 elems) exclusive scan; chunk totals out.
__global__ __launch_bounds__(256) void scanA_kernel(const int* __restrict__ cnt,
                                                    int* __restrict__ row_ptr,
                                                    int* __restrict__ chunk_sums) {
    __shared__ int sh[256];
    int b = blockIdx.x, t = threadIdx.x;
    int base = b * 1024 + t * 4;
    int v0 = (base + 0 < N_NODES) ? cnt[base + 0] : 0;
    int v1 = (base + 1 < N_NODES) ? cnt[base + 1] : 0;
    int v2 = (base + 2 < N_NODES) ? cnt[base + 2] : 0;
    int v3 = (base + 3 < N_NODES) ? cnt[base + 3] : 0;
    int s = v0 + v1 + v2 + v3;
    sh[t] = s;
    __syncthreads();
    for (int off = 1; off < 256; off <<= 1) {
        int x = (t >= off) ? sh[t - off] : 0;
        __syncthreads();
        sh[t] += x;
        __syncthreads();
    }
    int excl = sh[t] - s;
    if (t == 255) chunk_sums[b] = sh[255];
    int run = excl;
    if (base + 0 < N_NODES) { row_ptr[base + 0] = run; run += v0; }
    if (base + 1 < N_NODES) { row_ptr[base + 1] = run; run += v1; }
    if (base + 2 < N_NODES) { row_ptr[base + 2] = run; run += v2; }
    if (base + 3 < N_NODES) { row_ptr[base + 3] = run; run += v3; }
}

__global__ void scanB_kernel(int* __restrict__ chunk_sums) {
    if (threadIdx.x == 0 && blockIdx.x == 0) {
        int run = 0;
        for (int i = 0; i < NCHUNKS; ++i) {
            int c = chunk_sums[i];
            chunk_sums[i] = run;
            run += c;
        }
    }
}

__global__ __launch_bounds__(256) void scanC_kernel(int* __restrict__ row_ptr,
                                                    int* __restrict__ cursor,
                                                    const int* __restrict__ chunk_offs) {
    int i = blockIdx.x * blockDim.x + threadIdx.x;
    if (i < N_NODES) {
        int v = row_ptr[i] + chunk_offs[i >> 10];
        row_ptr[i] = v;
        cursor[i] = v;
    } else if (i == N_NODES) {
        row_ptr[i] = NNZ_C;
    }
}

__global__ __launch_bounds__(256) void scatter_kernel(const int* __restrict__ src,
                                                      const int* __restrict__ dst,
                                                      const float* __restrict__ val,
                                                      int2* __restrict__ packed,
                                                      int* __restrict__ cursor) {
    int i = blockIdx.x * blockDim.x + threadIdx.x;
    int stride = gridDim.x * blockDim.x;
    for (; i < NNZ_C; i += stride) {
        int d = dst[i];
        int p = atomicAdd(&cursor[d], 1);
        packed[p] = make_int2(src[i], __float_as_int(val[i]));
    }
}

// ---------------- X = concat(uemb, iemb) ----------------

__global__ __launch_bounds__(256) void concat_kernel(const float* __restrict__ uemb,
                                                     const float* __restrict__ iemb,
                                                     float4* __restrict__ X4) {
    // total floats: 150000*64 = 9,600,000 -> 2,400,000 float4
    const int NU4 = NUM_USERS * DIM / 4;   // 1,600,000
    const int NT4 = N_NODES * DIM / 4;     // 2,400,000
    int i = blockIdx.x * blockDim.x + threadIdx.x;
    int stride = gridDim.x * blockDim.x;
    const float4* u4 = (const float4*)uemb;
    const float4* i4 = (const float4*)iemb;
    for (; i < NT4; i += stride)
        X4[i] = (i < NU4) ? u4[i] : i4[i - NU4];
}

// ---------------- SpMM (gather, 1 wave per dst node) ----------------
// Per 64-edge chunk: coalesced edge load (lane -> packed[base+lane]),
// then readlane-broadcast (uniform index -> SGPR src row / SGPR weight),
// 8 gathers in flight per wave.

__global__ __launch_bounds__(256) void spmm_kernel(const int2* __restrict__ packed,
                                                   const int* __restrict__ row_ptr,
                                                   const float* __restrict__ xin,
                                                   float* __restrict__ xout) {
    int gtid = blockIdx.x * blockDim.x + threadIdx.x;
    int node = gtid >> 6;
    int lane = threadIdx.x & 63;
    if (node >= N_NODES) return;
    int beg = row_ptr[node];
    int end = row_ptr[node + 1];
    const float* xl = xin + lane;
    float acc = 0.f;
    for (int base = beg; base < end; base += 64) {
        int n = end - base;
        n = n > 64 ? 64 : n;
        int2 p = make_int2(0, 0);
        if (lane < n) p = packed[base + lane];
        for (int j = 0; j < n; j += 8) {
            int s0 = __builtin_amdgcn_readlane(p.x, j + 0);
            int s1 = __builtin_amdgcn_readlane(p.x, j + 1);
            int s2 = __builtin_amdgcn_readlane(p.x, j + 2);
            int s3 = __builtin_amdgcn_readlane(p.x, j + 3);
            int s4 = __builtin_amdgcn_readlane(p.x, j + 4);
            int s5 = __builtin_amdgcn_readlane(p.x, j + 5);
            int s6 = __builtin_amdgcn_readlane(p.x, j + 6);
            int s7 = __builtin_amdgcn_readlane(p.x, j + 7);
            float v0 = __int_as_float(__builtin_amdgcn_readlane(p.y, j + 0));
            float v1 = __int_as_float(__builtin_amdgcn_readlane(p.y, j + 1));
            float v2 = __int_as_float(__builtin_amdgcn_readlane(p.y, j + 2));
            float v3 = __int_as_float(__builtin_amdgcn_readlane(p.y, j + 3));
            float v4 = __int_as_float(__builtin_amdgcn_readlane(p.y, j + 4));
            float v5 = __int_as_float(__builtin_amdgcn_readlane(p.y, j + 5));
            float v6 = __int_as_float(__builtin_amdgcn_readlane(p.y, j + 6));
            float v7 = __int_as_float(__builtin_amdgcn_readlane(p.y, j + 7));
            float a0 = xl[(size_t)s0 * DIM];
            float a1 = xl[(size_t)s1 * DIM];
            float a2 = xl[(size_t)s2 * DIM];
            float a3 = xl[(size_t)s3 * DIM];
            float a4 = xl[(size_t)s4 * DIM];
            float a5 = xl[(size_t)s5 * DIM];
            float a6 = xl[(size_t)s6 * DIM];
            float a7 = xl[(size_t)s7 * DIM];
            acc = fmaf(v0, a0, acc);
            acc = fmaf(v1, a1, acc);
            acc = fmaf(v2, a2, acc);
            acc = fmaf(v3, a3, acc);
            acc = fmaf(v4, a4, acc);
            acc = fmaf(v5, a5, acc);
            acc = fmaf(v6, a6, acc);
            acc = fmaf(v7, a7, acc);
        }
    }
    xout[(size_t)node * DIM + lane] = acc;
}

// ---------------- selected-row accumulation + dot ----------------

__global__ __launch_bounds__(256) void init_sel_kernel(const int* __restrict__ users,
                                                       const int* __restrict__ items,
                                                       const float* __restrict__ X,
                                                       float* __restrict__ acc_sel) {
    int gtid = blockIdx.x * blockDim.x + threadIdx.x;
    int idx = gtid >> 6;
    int lane = threadIdx.x & 63;
    if (idx >= 2 * BATCH_C) return;
    int node = (idx < BATCH_C) ? users[idx] : (NUM_USERS + items[idx - BATCH_C]);
    acc_sel[(size_t)idx * DIM + lane] = X[(size_t)node * DIM + lane];
}

__global__ __launch_bounds__(256) void add_sel_kernel(const int* __restrict__ users,
                                                      const int* __restrict__ items,
                                                      const float* __restrict__ h,
                                                      float* __restrict__ acc_sel) {
    int gtid = blockIdx.x * blockDim.x + threadIdx.x;
    int idx = gtid >> 6;
    int lane = threadIdx.x & 63;
    if (idx >= 2 * BATCH_C) return;
    int node = (idx < BATCH_C) ? users[idx] : (NUM_USERS + items[idx - BATCH_C]);
    acc_sel[(size_t)idx * DIM + lane] += h[(size_t)node * DIM + lane];
}

__global__ __launch_bounds__(256) void dot_kernel(const float* __restrict__ acc_sel,
                                                  float* __restrict__ out) {
    int gtid = blockIdx.x * blockDim.x + threadIdx.x;
    int b = gtid >> 6;
    int lane = threadIdx.x & 63;
    if (b >= BATCH_C) return;
    float u = acc_sel[(size_t)b * DIM + lane];
    float v = acc_sel[(size_t)(BATCH_C + b) * DIM + lane];
    float p = u * v;
    for (int off = 32; off > 0; off >>= 1) p += __shfl_xor(p, off);
    if (lane == 0) out[b] = p * 0.0625f;  // (1/4)^2 for the two light_out rows
}

// ---------------- launch ----------------

extern "C" void kernel_launch(void* const* d_in, const int* in_sizes, int n_in,
                              void* d_out, int out_size, void* d_ws, size_t ws_size,
                              hipStream_t stream) {
    const int*   users = (const int*)d_in[0];
    const int*   items = (const int*)d_in[1];
    const float* uemb  = (const float*)d_in[2];
    const float* iemb  = (const float*)d_in[3];
    const int*   esrc  = (const int*)d_in[4];
    const int*   edst  = (const int*)d_in[5];
    const float* eval  = (const float*)d_in[6];
    float*       out   = (float*)d_out;

    char* ws = (char*)d_ws;
    // layout (bytes):
    int2*  packed   = (int2*)(ws + 0);             // 10M * 8B = 80,000,000
    float* X        = (float*)(ws + 80000000);     // 38,400,000  (x0, later layer2)
    float* hA       = (float*)(ws + 118400000);    // 38,400,000  (layer1, later layer3)
    float* acc_sel  = (float*)(ws + 156800000);    // 8192*64*4 = 2,097,152
    int*   row_ptr  = (int*)(ws + 158897152);      // 600,004 (pad to 600,016)
    int*   cursor   = (int*)(ws + 159497168);      // 600,000
    int*   chunk_s  = (int*)(ws + 160097168);      // 1,024
    // total ~160.1 MB

    // 1) CSR build (edge structure shared by all 3 layers)
    hipMemsetAsync(cursor, 0, N_NODES * sizeof(int), stream);
    count_kernel<<<2048, 256, 0, stream>>>(edst, cursor);
    scanA_kernel<<<NCHUNKS, 256, 0, stream>>>(cursor, row_ptr, chunk_s);
    scanB_kernel<<<1, 64, 0, stream>>>(chunk_s);
    scanC_kernel<<<(N_NODES + 256) / 256, 256, 0, stream>>>(row_ptr, cursor, chunk_s);
    scatter_kernel<<<2048, 256, 0, stream>>>(esrc, edst, eval, packed, cursor);

    // 2) X = concat(uemb, iemb); selected-row init (layer-0 term)
    concat_kernel<<<2048, 256, 0, stream>>>(uemb, iemb, (float4*)X);
    init_sel_kernel<<<(2 * BATCH_C) / 4, 256, 0, stream>>>(users, items, X, acc_sel);

    // 3) three SpMM layers; accumulate selected rows after each.
    //    Buffers: X -> hA -> X -> hA  (x0 dead after spmm1, layer1 dead after spmm2)
    const int spmm_blocks = N_NODES / 4;  // 1 wave per node, 4 waves per block
    spmm_kernel<<<spmm_blocks, 256, 0, stream>>>(packed, row_ptr, X, hA);
    add_sel_kernel<<<(2 * BATCH_C) / 4, 256, 0, stream>>>(users, items, hA, acc_sel);
    spmm_kernel<<<spmm_blocks, 256, 0, stream>>>(packed, row_ptr, hA, X);
    add_sel_kernel<<<(2 * BATCH_C) / 4, 256, 0, stream>>>(users, items, X, acc_sel);
    spmm_kernel<<<spmm_blocks, 256, 0, stream>>>(packed, row_ptr, X, hA);
    add_sel_kernel<<<(2 * BATCH_C) / 4, 256, 0, stream>>>(users, items, hA, acc_sel);

    // 4) final dot products
    dot_kernel<<<BATCH_C / 4, 256, 0, stream>>>(acc_sel, out);
}